// Round 7
// baseline (13551.193 us; speedup 1.0000x reference)
//
#include <hip/hip_runtime.h>

// RVQ encoder — bit-exact emulation of the harness numpy reference under the
// BLAS hypothesis: einsums evaluated via OpenBLAS sgemm (k-serial FMA chains,
// Q=384 panel splits), np.sum via scalar pairwise 8-accumulator blocks.
//  * E(d2) (K=128):   acc = fmaf(r[k], c[k], acc), k ascending, single chain
//  * x-proj (K=512):  (chain(0:384) + chain(384:512)) + in_b
//  * sem-bias(K=4096):((ch0+ch1)+...)+ch10 (10x384+256) + sem_b
//  * A,C:             numpy pairwise 8-acc, ((s0+s1)+(s2+s3))+((s4+s5)+(s6+s7))
//  * d2 = (A - 2f*E) + C ; argmin = first minimum (lowest index on ties)
// Surrogate fmaf scan shortlists top-4 per wave; candidates re-scored exactly.
//
// ws: biasg f32[10240] | x f32[4194304] | norms f32[32768] | part f64[512]
// d_out (f32): quantized[4194304] | indices-as-f32[1048576] | closs[1]

// ---- np-exact helpers --------------------------------------------------------

// numpy pairwise scalar 8-acc sum of squares, n=128
__device__ __forceinline__ float np_sumsq128(const float r[128]) {
#pragma clang fp contract(off)
  float s0 = r[0] * r[0], s1 = r[1] * r[1], s2 = r[2] * r[2], s3 = r[3] * r[3];
  float s4 = r[4] * r[4], s5 = r[5] * r[5], s6 = r[6] * r[6], s7 = r[7] * r[7];
#pragma unroll
  for (int t = 1; t < 16; ++t) {
    s0 += r[8 * t + 0] * r[8 * t + 0];
    s1 += r[8 * t + 1] * r[8 * t + 1];
    s2 += r[8 * t + 2] * r[8 * t + 2];
    s3 += r[8 * t + 3] * r[8 * t + 3];
    s4 += r[8 * t + 4] * r[8 * t + 4];
    s5 += r[8 * t + 5] * r[8 * t + 5];
    s6 += r[8 * t + 6] * r[8 * t + 6];
    s7 += r[8 * t + 7] * r[8 * t + 7];
  }
  return ((s0 + s1) + (s2 + s3)) + ((s4 + s5) + (s6 + s7));
}

// BLAS-microkernel dot: single serial FMA chain, k ascending (K=128)
__device__ __forceinline__ float np_d2_blas(const float r[128],
                                            const float* __restrict__ cp,
                                            float A, float C) {
  float E = 0.f;
#pragma unroll
  for (int i = 0; i < 128; ++i) E = fmaf(r[i], cp[i], E);
  {
#pragma clang fp contract(off)
    float t = A - 2.0f * E;   // 2*E exact; single rounding either way
    return t + C;
  }
}

__device__ __forceinline__ float np_add_scaled(float r, float b) {
#pragma clang fp contract(off)
  float t = 0.1f * b;
  return r + t;
}

__device__ __forceinline__ float np_ste(float x, float q) {
#pragma clang fp contract(off)
  float t = q - x;
  return x + t;
}

// ---- A: per-code norms (np pairwise 8-acc) -----------------------------------
__global__ __launch_bounds__(256) void code_norms_np(const float* __restrict__ cb,
                                                     float* __restrict__ norms) {
  int i = blockIdx.x * 256 + threadIdx.x;            // k*1024+c
  const float* a = cb + (size_t)i * 128;
  float v[128];
#pragma unroll
  for (int j = 0; j < 32; ++j) {
    float4 t = ((const float4*)a)[j];
    v[4 * j] = t.x; v[4 * j + 1] = t.y; v[4 * j + 2] = t.z; v[4 * j + 3] = t.w;
  }
  norms[i] = np_sumsq128(v);
}

// ---- B: x = af @ in_w^T + in_b via sgemm semantics (K=512 -> 384+128) --------
__global__ __launch_bounds__(256, 2) void xproj_blas(const float* __restrict__ af,
                                                     const float* __restrict__ in_w,
                                                     const float* __restrict__ in_b,
                                                     float* __restrict__ x) {
  int row = blockIdx.x * 256 + threadIdx.x;          // 0..32767
  const float* ar = af + (size_t)row * 512;
  for (int oc = 0; oc < 8; ++oc) {                   // 16 outputs per group
    float accA[16], accB[16];
#pragma unroll
    for (int o = 0; o < 16; ++o) { accA[o] = 0.f; accB[o] = 0.f; }
    for (int kc = 0; kc < 4; ++kc) {                 // 128-element k chunks
      float a[128];
      const float4* ap = (const float4*)(ar + kc * 128);
#pragma unroll
      for (int i = 0; i < 32; ++i) {
        float4 v = ap[i];
        a[4 * i] = v.x; a[4 * i + 1] = v.y; a[4 * i + 2] = v.z; a[4 * i + 3] = v.w;
      }
      if (kc < 3) {                                  // k = 0..383 -> panel A
#pragma unroll
        for (int o = 0; o < 16; ++o) {
          const float* wr = in_w + (size_t)(oc * 16 + o) * 512 + kc * 128;
          float acc = accA[o];
#pragma unroll
          for (int m = 0; m < 128; ++m) acc = fmaf(a[m], wr[m], acc);
          accA[o] = acc;
        }
      } else {                                       // k = 384..511 -> panel B
#pragma unroll
        for (int o = 0; o < 16; ++o) {
          const float* wr = in_w + (size_t)(oc * 16 + o) * 512 + kc * 128;
          float acc = accB[o];
#pragma unroll
          for (int m = 0; m < 128; ++m) acc = fmaf(a[m], wr[m], acc);
          accB[o] = acc;
        }
      }
    }
    {
#pragma clang fp contract(off)
#pragma unroll
      for (int o = 0; o < 16; ++o) {
        float E = accA[o] + accB[o];                 // panel junction add
        x[(size_t)row * 128 + oc * 16 + o] = E + in_b[oc * 16 + o];
      }
    }
  }
}

// ---- C: sem_bias via sgemm semantics (K=4096 -> 10x384 + 256 panels) ---------
__global__ __launch_bounds__(256) void sembias_blas(const float* __restrict__ sem_w,
                                                    const float* __restrict__ sem_b,
                                                    const float* __restrict__ ctx,
                                                    float* __restrict__ biasg) {
  int tid = blockIdx.x * 256 + threadIdx.x;          // 0..1279 = k*128+d
  if (tid >= 1280) return;
  int k = tid >> 7, d = tid & 127;
  const float* w = sem_w + (size_t)tid * 4096;
  float val[8];
  for (int j = 0; j < 11; ++j) {                     // sgemm k-panels
    int p0 = j * 384;
    int len = (j < 10) ? 384 : 256;                  // 10*384 + 256 = 4096
    float acc[8] = {0.f, 0.f, 0.f, 0.f, 0.f, 0.f, 0.f, 0.f};
    for (int i = 0; i < len; ++i) {
      float wv = w[p0 + i];
#pragma unroll
      for (int b = 0; b < 8; ++b)
        acc[b] = fmaf(wv, ctx[(size_t)b * 4096 + p0 + i], acc[b]);
    }
    {
#pragma clang fp contract(off)
      if (j == 0) {
#pragma unroll
        for (int b = 0; b < 8; ++b) val[b] = acc[b];
      } else {
#pragma unroll
        for (int b = 0; b < 8; ++b) val[b] = val[b] + acc[b];
      }
    }
  }
  {
#pragma clang fp contract(off)
#pragma unroll
    for (int b = 0; b < 8; ++b)
      biasg[((size_t)k * 8 + b) * 128 + d] = val[b] + sem_b[k * 128 + d];
  }
}

// ---- D: main 32-step loop, np-exact trajectory in r[128] ---------------------
__global__ __launch_bounds__(256, 2) void rvq_main(const float* __restrict__ cb,
                                                   const float* __restrict__ norms,
                                                   const float* __restrict__ biasg,
                                                   const float* __restrict__ x,
                                                   float* __restrict__ outIdx) {
  const int lane = threadIdx.x & 63;
  const int wave = __builtin_amdgcn_readfirstlane(threadIdx.x >> 6);
  const int wg = blockIdx.x;                          // 0..511
  const int row = (wg << 6) + lane;
  const int b = wg >> 6;

  __shared__ float biasS[10 * 128];
  __shared__ float candV[4][64];
  __shared__ int candI[4][64];
  __shared__ int chosen[64];

  for (int t = threadIdx.x; t < 10 * 128; t += 256) {
    int kk = t >> 7, d = t & 127;
    biasS[t] = biasg[((size_t)kk * 8 + b) * 128 + d];
  }

  float r[128];
  {
    const float4* xp = (const float4*)(x + (size_t)row * 128);
#pragma unroll
    for (int i = 0; i < 32; ++i) {
      float4 v = xp[i];
      r[4 * i] = v.x; r[4 * i + 1] = v.y; r[4 * i + 2] = v.z; r[4 * i + 3] = v.w;
    }
  }
  __syncthreads();

  const int c0 = wave << 8;
  for (int k = 0; k < 32; ++k) {
    if (k < 10) {
#pragma unroll
      for (int d = 0; d < 128; ++d) r[d] = np_add_scaled(r[d], biasS[(k << 7) + d]);
    }
    float A = np_sumsq128(r);
    const float* cbk = cb + ((size_t)k << 17);
    const float* nk = norms + (k << 10);
    // surrogate fmaf scan: per-wave top-4 shortlist (branchless insertion)
    float b0 = 3.4e38f, b1 = 3.4e38f, b2 = 3.4e38f, b3 = 3.4e38f;
    int i0 = c0, i1 = c0, i2 = c0, i3 = c0;
    for (int c = c0; c < c0 + 256; ++c) {
      const float* cp = cbk + (c << 7);
      float a0 = 0.f, a1 = 0.f, a2 = 0.f, a3 = 0.f;
#pragma unroll
      for (int i = 0; i < 32; ++i) {
        a0 = fmaf(r[4 * i + 0], cp[4 * i + 0], a0);
        a1 = fmaf(r[4 * i + 1], cp[4 * i + 1], a1);
        a2 = fmaf(r[4 * i + 2], cp[4 * i + 2], a2);
        a3 = fmaf(r[4 * i + 3], cp[4 * i + 3], a3);
      }
      float s = nk[c] - 2.0f * ((a0 + a1) + (a2 + a3));
      bool lt0 = s < b0, lt1 = s < b1, lt2 = s < b2, lt3 = s < b3;
      b3 = lt2 ? b2 : (lt3 ? s : b3);  i3 = lt2 ? i2 : (lt3 ? c : i3);
      b2 = lt1 ? b1 : (lt2 ? s : b2);  i2 = lt1 ? i1 : (lt2 ? c : i2);
      b1 = lt0 ? b0 : (lt1 ? s : b1);  i1 = lt0 ? i0 : (lt1 ? c : i1);
      b0 = lt0 ? s : b0;               i0 = lt0 ? c : i0;
    }
    // exact rescoring: 4 interleaved serial FMA chains (ILP across candidates)
    const float* p0 = cbk + ((size_t)i0 << 7);
    const float* p1 = cbk + ((size_t)i1 << 7);
    const float* p2 = cbk + ((size_t)i2 << 7);
    const float* p3 = cbk + ((size_t)i3 << 7);
    float E0 = 0.f, E1 = 0.f, E2 = 0.f, E3 = 0.f;
#pragma unroll
    for (int d = 0; d < 128; ++d) {
      float rd = r[d];
      E0 = fmaf(rd, p0[d], E0);
      E1 = fmaf(rd, p1[d], E1);
      E2 = fmaf(rd, p2[d], E2);
      E3 = fmaf(rd, p3[d], E3);
    }
    float e0, e1, e2, e3;
    {
#pragma clang fp contract(off)
      float t0 = A - 2.0f * E0; e0 = t0 + nk[i0];
      float t1 = A - 2.0f * E1; e1 = t1 + nk[i1];
      float t2 = A - 2.0f * E2; e2 = t2 + nk[i2];
      float t3 = A - 2.0f * E3; e3 = t3 + nk[i3];
    }
    float bv = e0; int bi = i0;
    if (e1 < bv || (e1 == bv && i1 < bi)) { bv = e1; bi = i1; }
    if (e2 < bv || (e2 == bv && i2 < bi)) { bv = e2; bi = i2; }
    if (e3 < bv || (e3 == bv && i3 < bi)) { bv = e3; bi = i3; }
    candV[wave][lane] = bv;
    candI[wave][lane] = bi;
    __syncthreads();
    if (wave == 0) {
      float mv = candV[0][lane];
      int mi = candI[0][lane];
#pragma unroll
      for (int w = 1; w < 4; ++w) {
        float v = candV[w][lane];
        int ci = candI[w][lane];
        if (v < mv || (v == mv && ci < mi)) { mv = v; mi = ci; }
      }
      chosen[lane] = mi;
      outIdx[(k << 15) + row] = (float)mi;
    }
    __syncthreads();
    const float* q = cbk + ((size_t)chosen[lane] << 7);
#pragma unroll
    for (int d = 0; d < 128; ++d) r[d] = r[d] - q[d];   // single sub, exact
  }
}

// ---- E: quantized (fp32 k-order accumulate + STE) + closs partials -----------
__global__ __launch_bounds__(256) void quant_closs(const float* __restrict__ cb,
                                                   const float* __restrict__ x,
                                                   const float* __restrict__ idxF,
                                                   float* __restrict__ outQ,
                                                   double* __restrict__ partials) {
  int gid = blockIdx.x * 256 + threadIdx.x;          // 0..131071
  int row = gid >> 2;
  int d0 = (gid & 3) << 5;
  const float* xr = x + (size_t)row * 128 + d0;
  float xv[32], qv[32];
#pragma unroll
  for (int i = 0; i < 32; ++i) { xv[i] = xr[i]; qv[i] = 0.f; }
  double cl = 0.0;
  for (int k = 0; k < 32; ++k) {
    int c = (int)idxF[(k << 15) + row];
    const float* qp = cb + ((size_t)k << 17) + ((size_t)c << 7) + d0;
#pragma unroll
    for (int i = 0; i < 32; ++i) {
      float v = qp[i];
      qv[i] = qv[i] + v;                  // fp32 adds in k-order (np order)
      float e = v - xv[i];
      cl += (double)e * (double)e;
    }
  }
  float* op = outQ + (size_t)row * 128 + d0;
#pragma unroll
  for (int i = 0; i < 32; ++i) op[i] = np_ste(xv[i], qv[i]);
  __shared__ double red[256];
  red[threadIdx.x] = cl;
  __syncthreads();
  for (int s = 128; s > 0; s >>= 1) {
    if (threadIdx.x < s) red[threadIdx.x] += red[threadIdx.x + s];
    __syncthreads();
  }
  if (threadIdx.x == 0) partials[blockIdx.x] = red[0];
}

// ---- F: final closs reduction ------------------------------------------------
__global__ __launch_bounds__(256) void closs_final(const double* __restrict__ partials,
                                                   float* __restrict__ out) {
  __shared__ double red[256];
  red[threadIdx.x] = partials[threadIdx.x] + partials[threadIdx.x + 256];
  __syncthreads();
  for (int s = 128; s > 0; s >>= 1) {
    if (threadIdx.x < s) red[threadIdx.x] += red[threadIdx.x + s];
    __syncthreads();
  }
  if (threadIdx.x == 0) out[0] = (float)(red[0] * (0.25 / 4194304.0));
}

extern "C" void kernel_launch(void* const* d_in, const int* in_sizes, int n_in,
                              void* d_out, int out_size, void* d_ws, size_t ws_size,
                              hipStream_t stream) {
  const float* af    = (const float*)d_in[0];
  const float* ctx   = (const float*)d_in[1];
  const float* in_w  = (const float*)d_in[2];
  const float* in_b  = (const float*)d_in[3];
  const float* cb    = (const float*)d_in[4];
  const float* sem_w = (const float*)d_in[5];
  const float* sem_b = (const float*)d_in[6];

  float* out     = (float*)d_out;
  float* outQ    = out;
  float* outIdx  = out + 4194304;
  float* outLoss = out + 5242880;

  float*  ws_bias  = (float*)d_ws;                    // 10240
  float*  ws_x     = ws_bias + 10240;                 // 4194304
  float*  ws_norms = ws_x + 4194304;                  // 32768
  double* ws_part  = (double*)(ws_norms + 32768);     // 512 doubles

  hipLaunchKernelGGL(code_norms_np, dim3(128), dim3(256), 0, stream, cb, ws_norms);
  hipLaunchKernelGGL(xproj_blas, dim3(128), dim3(256), 0, stream, af, in_w, in_b, ws_x);
  hipLaunchKernelGGL(sembias_blas, dim3(5), dim3(256), 0, stream, sem_w, sem_b, ctx,
                     ws_bias);
  hipLaunchKernelGGL(rvq_main, dim3(512), dim3(256), 0, stream, cb, ws_norms,
                     ws_bias, ws_x, outIdx);
  hipLaunchKernelGGL(quant_closs, dim3(512), dim3(256), 0, stream, cb, ws_x,
                     outIdx, outQ, ws_part);
  hipLaunchKernelGGL(closs_final, dim3(1), dim3(256), 0, stream, ws_part, outLoss);
}